// Round 1
// baseline (843.782 us; speedup 1.0000x reference)
//
#include <hip/hip_runtime.h>

#define SAMPLES 4
#define N 294912            // 2*384*384 elements per sample
#define NB 64               // loss histogram bins
#define CAP 8192            // candidate buffer per sample
#define R0 280165           // floor(0.95*(N-1))
#define SCALE 262144.0f     // 2^18 fixed point for soft-hist weights

// ---------------- pass 1: top-16-bit bucket histogram (per sample) ----------
__global__ __launch_bounds__(256) void k_hist(const float* __restrict__ gt,
                                              unsigned* __restrict__ hist) {
    int b = blockIdx.x;                       // 1152 blocks; 288 per sample
    int s = b / 288;
    const float4 v = ((const float4*)gt)[b * 256 + threadIdx.x];
    unsigned* h = hist + s * 65536;
    atomicAdd(&h[__float_as_uint(v.x) >> 16], 1u);
    atomicAdd(&h[__float_as_uint(v.y) >> 16], 1u);
    atomicAdd(&h[__float_as_uint(v.z) >> 16], 1u);
    atomicAdd(&h[__float_as_uint(v.w) >> 16], 1u);
}

// ---------------- pass 2: find bucket + cum-below for ranks R0, R0+1 --------
__global__ __launch_bounds__(1024) void k_scan(const unsigned* __restrict__ hist,
                                               unsigned* __restrict__ scanB) {
    int s = blockIdx.x, t = threadIdx.x;
    __shared__ unsigned S[1024];
    const unsigned* h = hist + s * 65536;
    int base = t * 64;
    unsigned sum = 0;
    for (int b = 0; b < 64; b++) sum += h[base + b];
    S[t] = sum;
    __syncthreads();
    for (int off = 1; off < 1024; off <<= 1) {     // Hillis-Steele inclusive scan
        unsigned v = (t >= off) ? S[t - off] : 0u;
        __syncthreads();
        S[t] += v;
        __syncthreads();
    }
    unsigned incl = S[t], before = incl - sum;
    for (int k = 0; k < 2; k++) {
        unsigned r = R0 + k;
        if (sum > 0 && before <= r && r < incl) {   // unique owner thread
            unsigned c = before;
            for (int b = 0; b < 64; b++) {
                unsigned c2 = c + h[base + b];
                if (r < c2) {
                    if (k == 0) { scanB[s * 3 + 0] = (unsigned)(base + b); scanB[s * 3 + 2] = c; }
                    else        { scanB[s * 3 + 1] = (unsigned)(base + b); }
                    break;
                }
                c = c2;
            }
        }
    }
}

// ---------------- pass 3: compact candidates in buckets [B0,B1] -------------
__global__ __launch_bounds__(256) void k_collect(const float* __restrict__ gt,
                                                 const unsigned* __restrict__ scanB,
                                                 unsigned* __restrict__ cnt,
                                                 float* __restrict__ cand) {
    int s = blockIdx.y;
    unsigned B0 = scanB[s * 3 + 0], B1 = scanB[s * 3 + 1];
    const float4 v = ((const float4*)gt)[s * (N / 4) + blockIdx.x * 256 + threadIdx.x];
    float vv[4] = {v.x, v.y, v.z, v.w};
    for (int q = 0; q < 4; q++) {
        unsigned t16 = __float_as_uint(vv[q]) >> 16;
        if (t16 >= B0 && t16 <= B1) {
            unsigned p = atomicAdd(&cnt[s], 1u);
            if (p < CAP) cand[s * CAP + p] = vv[q];
        }
    }
}

// ---------------- pass 4: exact order stats among candidates ----------------
__global__ __launch_bounds__(1024) void k_select(const unsigned* __restrict__ cnt,
                                                 const unsigned* __restrict__ scanB,
                                                 const float* __restrict__ cand,
                                                 float* __restrict__ maxv) {
    int s = blockIdx.x, t = threadIdx.x;
    __shared__ float C[CAP];
    __shared__ float vsel[2];
    unsigned M = cnt[s];
    if (M > CAP) M = CAP;
    for (unsigned i = t; i < M; i += 1024) C[i] = cand[s * CAP + i];
    if (t < 2) vsel[t] = 0.f;
    __syncthreads();
    long long cum = (long long)scanB[s * 3 + 2];
    long long t0 = (long long)R0 - cum, t1 = t0 + 1;
    float mv[8]; int nm = 0;
    for (unsigned i = t; i < M; i += 1024) mv[nm++] = C[i];
    int c[8] = {0,0,0,0,0,0,0,0}, e[8] = {0,0,0,0,0,0,0,0};
    for (unsigned j = 0; j < M; j++) {
        float u = C[j];
        for (int q = 0; q < nm; q++) { c[q] += (u < mv[q]); e[q] += (u == mv[q]); }
    }
    for (int q = 0; q < nm; q++) {
        if (c[q] <= t0 && t0 < c[q] + e[q]) vsel[0] = mv[q];
        if (c[q] <= t1 && t1 < c[q] + e[q]) vsel[1] = mv[q];
    }
    __syncthreads();
    if (t == 0) {
        double pos   = 0.95 * (double)(N - 1);     // 280165.45
        double gamma = pos - (double)R0;
        double v = (double)vsel[0] + gamma * ((double)vsel[1] - (double)vsel[0]);
        maxv[s] = (float)v;
    }
}

// ---------------- pass 5: soft (triangular) histograms ----------------------
__global__ __launch_bounds__(256) void k_soft(const float* __restrict__ pred,
                                              const float* __restrict__ gt,
                                              const float* __restrict__ maxv,
                                              unsigned* __restrict__ pH,
                                              unsigned* __restrict__ gH) {
    int y = blockIdx.y, s = y >> 1, which = y & 1;
    const float* src = which ? gt : pred;
    __shared__ unsigned wh[4][NB];
    int t = threadIdx.x, w = t >> 6;
    for (int i = t; i < 4 * NB; i += 256) ((unsigned*)wh)[i] = 0;
    __syncthreads();
    float bw  = maxv[s] * (1.0f / 64.0f);
    float inv = 1.0f / bw;
    const float4* s4 = (const float4*)(src + s * N);
    int base = blockIdx.x * 1024;                  // in float4 units
    for (int k = 0; k < 4; k++) {
        float4 v = s4[base + k * 256 + t];
        float vv[4] = {v.x, v.y, v.z, v.w};
        for (int q = 0; q < 4; q++) {
            float x = vv[q] * inv;                 // x = mag / bin_width >= 0
            int j0 = (int)x;
            float fr = x - (float)j0;
            if (j0 < NB)     atomicAdd(&wh[w][j0],     (unsigned)((1.0f - fr) * SCALE + 0.5f));
            if (j0 + 1 < NB) atomicAdd(&wh[w][j0 + 1], (unsigned)(fr * SCALE + 0.5f));
        }
    }
    __syncthreads();
    unsigned* dst = (which ? gH : pH) + s * NB;
    if (t < NB) {
        unsigned tot = wh[0][t] + wh[1][t] + wh[2][t] + wh[3][t];
        atomicAdd(&dst[t], tot);
    }
}

// ---------------- pass 6: normalize, weight, reduce -------------------------
__global__ __launch_bounds__(256) void k_final(const unsigned* __restrict__ pH,
                                               const unsigned* __restrict__ gH,
                                               float* __restrict__ out) {
    int t = threadIdx.x, s = t >> 6, l = t & 63;   // 4 waves, one per sample
    double ph = (double)pH[s * NB + l];
    double gh = (double)gH[s * NB + l];
    double hp = ph, hg = gh;
    for (int m = 1; m < 64; m <<= 1) { hp += __shfl_xor(hp, m, 64); hg += __shfl_xor(hg, m, 64); }
    double wj = exp(0.4 * (double)l / 64.0);
    double d  = fabs(ph / hp * wj - gh / hg * wj);
    for (int m = 1; m < 64; m <<= 1) d += __shfl_xor(d, m, 64);
    __shared__ double L[4];
    if (l == 0) L[s] = d / 64.0;
    __syncthreads();
    if (t == 0) out[0] = (float)((L[0] + L[1] + L[2] + L[3]) * 0.25);
}

extern "C" void kernel_launch(void* const* d_in, const int* in_sizes, int n_in,
                              void* d_out, int out_size, void* d_ws, size_t ws_size,
                              hipStream_t stream) {
    const float* pred = (const float*)d_in[0];
    const float* gt   = (const float*)d_in[1];
    float* out = (float*)d_out;

    // ws layout (u32 words): hist[4][65536] | pH[4][64] | gH[4][64] | cnt[4]
    //                        | scanB[4][3] | maxv[4] (f32) | cand[4][CAP] (f32)
    unsigned* ws    = (unsigned*)d_ws;
    unsigned* hist  = ws;
    unsigned* pH    = ws + SAMPLES * 65536;
    unsigned* gH    = pH + SAMPLES * NB;
    unsigned* cnt   = gH + SAMPLES * NB;
    unsigned* scanB = cnt + SAMPLES;
    float*    maxv  = (float*)(scanB + SAMPLES * 3);
    float*    cand  = maxv + SAMPLES;

    size_t zero_words = (size_t)SAMPLES * 65536 + 2 * SAMPLES * NB + SAMPLES;
    hipMemsetAsync(d_ws, 0, zero_words * sizeof(unsigned), stream);

    k_hist   <<<1152, 256, 0, stream>>>(gt, hist);
    k_scan   <<<SAMPLES, 1024, 0, stream>>>(hist, scanB);
    k_collect<<<dim3(288, SAMPLES), 256, 0, stream>>>(gt, scanB, cnt, cand);
    k_select <<<SAMPLES, 1024, 0, stream>>>(cnt, scanB, cand, maxv);
    k_soft   <<<dim3(72, 2 * SAMPLES), 256, 0, stream>>>(pred, gt, maxv, pH, gH);
    k_final  <<<1, 256, 0, stream>>>(pH, gH, out);
}

// Round 2
// 190.848 us; speedup vs baseline: 4.4212x; 4.4212x over previous
//
#include <hip/hip_runtime.h>

#define SAMPLES 4
#define N 294912            // 2*384*384 elements per sample
#define NB 64               // loss histogram bins
#define CAP 4096            // candidate buffer per sample (expected M ~1.2-2.4k)
#define R0 280165           // floor(0.95*(N-1))
#define P 16                // partial histograms per sample
#define HB 16384            // top-16-bit buckets (values < 2.0 -> bits>>16 < 16384)
#define SCALE 262144.0f     // 2^18 fixed point for soft-hist weights

// ---------------- pass 1: per-block LDS bucket histogram --------------------
__global__ __launch_bounds__(512) void k_hist(const float* __restrict__ gt,
                                              unsigned* __restrict__ hist) {
    int p = blockIdx.x, s = blockIdx.y, t = threadIdx.x;
    __shared__ unsigned H[HB];
    for (int i = 0; i < HB / (512 * 4); i++)            // 8 iters of uint4 zero
        ((uint4*)H)[i * 512 + t] = make_uint4(0, 0, 0, 0);
    __syncthreads();
    const float4* src = (const float4*)(gt + s * N) + p * (N / 4 / P);
    for (int i = 0; i < (N / 4 / P) / 512; i++) {       // 9 float4 per thread
        float4 v = src[i * 512 + t];
        unsigned b0 = __float_as_uint(v.x) >> 16; if (b0 > HB - 1) b0 = HB - 1;
        unsigned b1 = __float_as_uint(v.y) >> 16; if (b1 > HB - 1) b1 = HB - 1;
        unsigned b2 = __float_as_uint(v.z) >> 16; if (b2 > HB - 1) b2 = HB - 1;
        unsigned b3 = __float_as_uint(v.w) >> 16; if (b3 > HB - 1) b3 = HB - 1;
        atomicAdd(&H[b0], 1u); atomicAdd(&H[b1], 1u);
        atomicAdd(&H[b2], 1u); atomicAdd(&H[b3], 1u);
    }
    __syncthreads();
    unsigned* dst = hist + (size_t)(s * P + p) * HB;    // non-atomic partial write
    for (int i = 0; i < HB / (512 * 4); i++)
        ((uint4*)dst)[i * 512 + t] = ((const uint4*)H)[i * 512 + t];
}

// ---------------- pass 2: sum partials, scan, locate rank buckets -----------
__global__ __launch_bounds__(1024) void k_scan(const unsigned* __restrict__ hist,
                                               unsigned* __restrict__ scanB) {
    int s = blockIdx.x, t = threadIdx.x;
    __shared__ unsigned S[1024];
    const unsigned* base = hist + (size_t)s * P * HB + t * 16;
    unsigned sum = 0;
    #pragma unroll
    for (int p = 0; p < P; p++) {
        const uint4* q = (const uint4*)(base + (size_t)p * HB);
        #pragma unroll
        for (int r = 0; r < 4; r++) {
            uint4 v = q[r];
            sum += v.x + v.y + v.z + v.w;
        }
    }
    S[t] = sum;
    __syncthreads();
    for (int off = 1; off < 1024; off <<= 1) {          // Hillis-Steele inclusive
        unsigned v = (t >= off) ? S[t - off] : 0u;
        __syncthreads();
        S[t] += v;
        __syncthreads();
    }
    unsigned incl = S[t], before = incl - sum;
    for (int k = 0; k < 2; k++) {
        unsigned r = R0 + k;
        if (sum > 0 && before <= r && r < incl) {       // unique owner thread
            unsigned c = before;
            for (int b = 0; b < 16; b++) {              // re-read bins (keeps regs static)
                unsigned h = 0;
                for (int p = 0; p < P; p++) h += base[(size_t)p * HB + b];
                if (r < c + h) {
                    if (k == 0) { scanB[s * 3 + 0] = (unsigned)(t * 16 + b); scanB[s * 3 + 2] = c; }
                    else        { scanB[s * 3 + 1] = (unsigned)(t * 16 + b); }
                    break;
                }
                c += h;
            }
        }
    }
}

// ---------------- pass 3: compact candidates in buckets [B0,B1] -------------
__global__ __launch_bounds__(256) void k_collect(const float* __restrict__ gt,
                                                 const unsigned* __restrict__ scanB,
                                                 unsigned* __restrict__ cnt,
                                                 float* __restrict__ cand) {
    int s = blockIdx.y;
    unsigned B0 = scanB[s * 3 + 0], B1 = scanB[s * 3 + 1];
    const float4 v = ((const float4*)gt)[s * (N / 4) + blockIdx.x * 256 + threadIdx.x];
    float vv[4] = {v.x, v.y, v.z, v.w};
    #pragma unroll
    for (int q = 0; q < 4; q++) {
        unsigned t16 = __float_as_uint(vv[q]) >> 16;
        if (t16 >= B0 && t16 <= B1) {
            unsigned pp = atomicAdd(&cnt[s], 1u);
            if (pp < CAP) cand[s * CAP + pp] = vv[q];
        }
    }
}

// ---------------- pass 4: bitonic sort candidates in LDS, interpolate -------
__global__ __launch_bounds__(1024) void k_sort(const unsigned* __restrict__ cnt,
                                               const unsigned* __restrict__ scanB,
                                               const float* __restrict__ cand,
                                               float* __restrict__ maxv) {
    int s = blockIdx.x, t = threadIdx.x;
    __shared__ float C[CAP];
    unsigned M = cnt[s];
    if (M > CAP) M = CAP;
    for (int i = t; i < CAP; i += 1024)
        C[i] = (i < (int)M) ? cand[s * CAP + i] : 1e30f;   // pad sorts last
    __syncthreads();
    for (int k = 2; k <= CAP; k <<= 1) {
        for (int j = k >> 1; j > 0; j >>= 1) {
            for (int i = t; i < CAP; i += 1024) {
                int ixj = i ^ j;
                if (ixj > i) {
                    float a = C[i], b = C[ixj];
                    bool up = ((i & k) == 0);
                    if ((a > b) == up) { C[i] = b; C[ixj] = a; }
                }
            }
            __syncthreads();
        }
    }
    if (t == 0) {
        unsigned c0 = scanB[s * 3 + 2];
        unsigned t0 = (unsigned)R0 - c0;                   // rank within candidates
        double v0 = (double)C[t0], v1 = (double)C[t0 + 1];
        double pos   = 0.95 * (double)(N - 1);             // 280165.45
        double gamma = pos - (double)R0;
        maxv[s] = (float)(v0 + gamma * (v1 - v0));
    }
}

// ---------------- pass 5: soft (triangular) histograms ----------------------
__global__ __launch_bounds__(256) void k_soft(const float* __restrict__ pred,
                                              const float* __restrict__ gt,
                                              const float* __restrict__ maxv,
                                              unsigned* __restrict__ pH,
                                              unsigned* __restrict__ gH) {
    int y = blockIdx.y, s = y >> 1, which = y & 1;
    const float* src = which ? gt : pred;
    __shared__ unsigned wh[4][NB];
    int t = threadIdx.x, w = t >> 6;
    for (int i = t; i < 4 * NB; i += 256) ((unsigned*)wh)[i] = 0;
    __syncthreads();
    float bw  = maxv[s] * (1.0f / 64.0f);
    float inv = 1.0f / bw;
    const float4* s4 = (const float4*)(src + s * N);
    int base = blockIdx.x * 1024;                  // in float4 units
    for (int k = 0; k < 4; k++) {
        float4 v = s4[base + k * 256 + t];
        float vv[4] = {v.x, v.y, v.z, v.w};
        #pragma unroll
        for (int q = 0; q < 4; q++) {
            float x = vv[q] * inv;                 // x = mag / bin_width >= 0
            int j0 = (int)x;
            float fr = x - (float)j0;
            if (j0 < NB)     atomicAdd(&wh[w][j0],     (unsigned)((1.0f - fr) * SCALE + 0.5f));
            if (j0 + 1 < NB) atomicAdd(&wh[w][j0 + 1], (unsigned)(fr * SCALE + 0.5f));
        }
    }
    __syncthreads();
    unsigned* dst = (which ? gH : pH) + s * NB;
    if (t < NB) {
        unsigned tot = wh[0][t] + wh[1][t] + wh[2][t] + wh[3][t];
        atomicAdd(&dst[t], tot);
    }
}

// ---------------- pass 6: normalize, weight, reduce -------------------------
__global__ __launch_bounds__(256) void k_final(const unsigned* __restrict__ pH,
                                               const unsigned* __restrict__ gH,
                                               float* __restrict__ out) {
    int t = threadIdx.x, s = t >> 6, l = t & 63;   // 4 waves, one per sample
    double ph = (double)pH[s * NB + l];
    double gh = (double)gH[s * NB + l];
    double hp = ph, hg = gh;
    for (int m = 1; m < 64; m <<= 1) { hp += __shfl_xor(hp, m, 64); hg += __shfl_xor(hg, m, 64); }
    double wj = exp(0.4 * (double)l / 64.0);
    double d  = fabs(ph / hp * wj - gh / hg * wj);
    for (int m = 1; m < 64; m <<= 1) d += __shfl_xor(d, m, 64);
    __shared__ double L[4];
    if (l == 0) L[s] = d / 64.0;
    __syncthreads();
    if (t == 0) out[0] = (float)((L[0] + L[1] + L[2] + L[3]) * 0.25);
}

extern "C" void kernel_launch(void* const* d_in, const int* in_sizes, int n_in,
                              void* d_out, int out_size, void* d_ws, size_t ws_size,
                              hipStream_t stream) {
    const float* pred = (const float*)d_in[0];
    const float* gt   = (const float*)d_in[1];
    float* out = (float*)d_out;

    // ws layout (u32 words):
    //   [zeroed prefix] pH[4][64] | gH[4][64] | cnt[4] | scanB[4][3] | maxv[4]
    //   cand[4][CAP] (f32) | hist[4][P][HB]
    unsigned* ws    = (unsigned*)d_ws;
    unsigned* pH    = ws;
    unsigned* gH    = pH + SAMPLES * NB;
    unsigned* cnt   = gH + SAMPLES * NB;
    unsigned* scanB = cnt + SAMPLES;
    float*    maxv  = (float*)(scanB + SAMPLES * 3);
    float*    cand  = maxv + SAMPLES;
    unsigned* hist  = (unsigned*)(cand + SAMPLES * CAP);   // 16B-aligned (offset 532+16384 words)

    size_t zero_words = 2 * SAMPLES * NB + SAMPLES + SAMPLES * 3 + SAMPLES; // 532
    hipMemsetAsync(d_ws, 0, zero_words * sizeof(unsigned), stream);

    k_hist   <<<dim3(P, SAMPLES), 512, 0, stream>>>(gt, hist);
    k_scan   <<<SAMPLES, 1024, 0, stream>>>(hist, scanB);
    k_collect<<<dim3(288, SAMPLES), 256, 0, stream>>>(gt, scanB, cnt, cand);
    k_sort   <<<SAMPLES, 1024, 0, stream>>>(cnt, scanB, cand, maxv);
    k_soft   <<<dim3(72, 2 * SAMPLES), 256, 0, stream>>>(pred, gt, maxv, pH, gH);
    k_final  <<<1, 256, 0, stream>>>(pH, gH, out);
}

// Round 3
// 123.742 us; speedup vs baseline: 6.8189x; 1.5423x over previous
//
#include <hip/hip_runtime.h>

#define SAMPLES 4
#define N 294912            // 2*384*384 elements per sample
#define NB 64               // loss histogram bins
#define CAP 4096            // candidate buffer per sample (expected M ~1.2-2.4k)
#define R0 280165           // floor(0.95*(N-1))
#define P 16                // partial histograms per sample
#define HB 16384            // top-16-bit buckets (values < 2.0 -> bits>>16 < 16384)
#define HB2 (HB / 2)        // u32 words per packed partial (2 x u16 bins per word)
#define BLK_CAP 128         // per-block candidate staging
#define SCALE 262144.0f     // 2^18 fixed point for soft-hist weights

// ---------------- pass 1: per-block LDS u16-packed bucket histogram ---------
// per-block per-bin count <= 18432 < 2^16, so two bins pack into one u32.
__global__ __launch_bounds__(512) void k_hist(const float* __restrict__ gt,
                                              unsigned* __restrict__ hist) {
    int p = blockIdx.x, s = blockIdx.y, t = threadIdx.x;
    __shared__ unsigned H[HB2];                         // 32 KB
    #pragma unroll
    for (int i = 0; i < HB2 / (512 * 4); i++)           // 4 uint4 per thread
        ((uint4*)H)[i * 512 + t] = make_uint4(0, 0, 0, 0);
    __syncthreads();
    const float4* src = (const float4*)(gt + s * N) + p * (N / 4 / P);
    #pragma unroll
    for (int i = 0; i < (N / 4 / P) / 512; i++) {       // 9 float4 per thread
        float4 v = src[i * 512 + t];
        unsigned b0 = __float_as_uint(v.x) >> 16; if (b0 > HB - 1) b0 = HB - 1;
        unsigned b1 = __float_as_uint(v.y) >> 16; if (b1 > HB - 1) b1 = HB - 1;
        unsigned b2 = __float_as_uint(v.z) >> 16; if (b2 > HB - 1) b2 = HB - 1;
        unsigned b3 = __float_as_uint(v.w) >> 16; if (b3 > HB - 1) b3 = HB - 1;
        atomicAdd(&H[b0 >> 1], 1u << ((b0 & 1) << 4));
        atomicAdd(&H[b1 >> 1], 1u << ((b1 & 1) << 4));
        atomicAdd(&H[b2 >> 1], 1u << ((b2 & 1) << 4));
        atomicAdd(&H[b3 >> 1], 1u << ((b3 & 1) << 4));
    }
    __syncthreads();
    unsigned* dst = hist + (size_t)(s * P + p) * HB2;   // non-atomic partial write
    #pragma unroll
    for (int i = 0; i < HB2 / (512 * 4); i++)
        ((uint4*)dst)[i * 512 + t] = ((const uint4*)H)[i * 512 + t];
}

// ---------------- pass 2: sum partials, scan, locate rank buckets -----------
// also zeroes pH/gH/cnt for the later passes (replaces the memset dispatch).
__global__ __launch_bounds__(1024) void k_scan(const unsigned* __restrict__ hist,
                                               unsigned* __restrict__ scanB,
                                               unsigned* __restrict__ pH,
                                               unsigned* __restrict__ gH,
                                               unsigned* __restrict__ cnt) {
    int s = blockIdx.x, t = threadIdx.x;
    if (t < NB) { pH[s * NB + t] = 0u; gH[s * NB + t] = 0u; }
    if (t == 0) cnt[s] = 0u;
    __shared__ unsigned S[1024];
    const unsigned* base = hist + (size_t)s * P * HB2 + t * 8;  // bins [t*16, t*16+16)
    unsigned sum = 0;
    #pragma unroll
    for (int p = 0; p < P; p++) {
        const uint4* q = (const uint4*)(base + (size_t)p * HB2);
        uint4 a = q[0], b = q[1];
        sum += (a.x & 0xFFFFu) + (a.x >> 16) + (a.y & 0xFFFFu) + (a.y >> 16)
             + (a.z & 0xFFFFu) + (a.z >> 16) + (a.w & 0xFFFFu) + (a.w >> 16)
             + (b.x & 0xFFFFu) + (b.x >> 16) + (b.y & 0xFFFFu) + (b.y >> 16)
             + (b.z & 0xFFFFu) + (b.z >> 16) + (b.w & 0xFFFFu) + (b.w >> 16);
    }
    S[t] = sum;
    __syncthreads();
    for (int off = 1; off < 1024; off <<= 1) {          // Hillis-Steele inclusive
        unsigned v = (t >= off) ? S[t - off] : 0u;
        __syncthreads();
        S[t] += v;
        __syncthreads();
    }
    unsigned incl = S[t], before = incl - sum;
    for (int k = 0; k < 2; k++) {
        unsigned r = R0 + k;
        if (sum > 0 && before <= r && r < incl) {       // unique owner thread
            unsigned c = before;
            for (int b = 0; b < 16; b++) {
                unsigned h = 0;
                for (int p = 0; p < P; p++)
                    h += (base[(size_t)p * HB2 + (b >> 1)] >> ((b & 1) << 4)) & 0xFFFFu;
                if (r < c + h) {
                    if (k == 0) { scanB[s * 3 + 0] = (unsigned)(t * 16 + b); scanB[s * 3 + 2] = c; }
                    else        { scanB[s * 3 + 1] = (unsigned)(t * 16 + b); }
                    break;
                }
                c += h;
            }
        }
    }
}

// ---------------- pass 3: compact candidates, block-aggregated --------------
__global__ __launch_bounds__(256) void k_collect(const float* __restrict__ gt,
                                                 const unsigned* __restrict__ scanB,
                                                 unsigned* __restrict__ cnt,
                                                 float* __restrict__ cand) {
    int s = blockIdx.y, t = threadIdx.x;
    __shared__ float buf[BLK_CAP];
    __shared__ unsigned nloc, basep;
    if (t == 0) nloc = 0u;
    __syncthreads();
    unsigned B0 = scanB[s * 3 + 0], B1 = scanB[s * 3 + 1];
    const float4 v = ((const float4*)gt)[s * (N / 4) + blockIdx.x * 256 + t];
    float vv[4] = {v.x, v.y, v.z, v.w};
    #pragma unroll
    for (int q = 0; q < 4; q++) {
        unsigned t16 = __float_as_uint(vv[q]) >> 16;
        if (t16 >= B0 && t16 <= B1) {
            unsigned p = atomicAdd(&nloc, 1u);          // LDS atomic, block-local
            if (p < BLK_CAP) buf[p] = vv[q];
        }
    }
    __syncthreads();
    unsigned n = nloc < BLK_CAP ? nloc : BLK_CAP;
    if (t == 0 && n) basep = atomicAdd(&cnt[s], n);     // ONE global atomic/block
    __syncthreads();
    if (t < n) {
        unsigned pp = basep + t;
        if (pp < CAP) cand[s * CAP + pp] = buf[t];
    }
}

// ---------------- pass 4: bitonic sort candidates in LDS, interpolate -------
__global__ __launch_bounds__(1024) void k_sort(const unsigned* __restrict__ cnt,
                                               const unsigned* __restrict__ scanB,
                                               const float* __restrict__ cand,
                                               float* __restrict__ maxv) {
    int s = blockIdx.x, t = threadIdx.x;
    __shared__ float C[CAP];
    unsigned M = cnt[s];
    if (M > CAP) M = CAP;
    int K = 1024;                                       // pow2 sort size >= M
    while (K < (int)M) K <<= 1;
    for (int i = t; i < K; i += 1024)
        C[i] = (i < (int)M) ? cand[s * CAP + i] : 1e30f;
    __syncthreads();
    for (int k = 2; k <= K; k <<= 1) {
        for (int j = k >> 1; j > 0; j >>= 1) {
            for (int i = t; i < K; i += 1024) {
                int ixj = i ^ j;
                if (ixj > i) {
                    float a = C[i], b = C[ixj];
                    bool up = ((i & k) == 0);
                    if ((a > b) == up) { C[i] = b; C[ixj] = a; }
                }
            }
            __syncthreads();
        }
    }
    if (t == 0) {
        unsigned c0 = scanB[s * 3 + 2];
        unsigned t0 = (unsigned)R0 - c0;                // rank within candidates
        double v0 = (double)C[t0], v1 = (double)C[t0 + 1];
        double pos   = 0.95 * (double)(N - 1);          // 280165.45
        double gamma = pos - (double)R0;
        maxv[s] = (float)(v0 + gamma * (v1 - v0));
    }
}

// ---------------- pass 5: soft (triangular) histograms ----------------------
__global__ __launch_bounds__(256) void k_soft(const float* __restrict__ pred,
                                              const float* __restrict__ gt,
                                              const float* __restrict__ maxv,
                                              unsigned* __restrict__ pH,
                                              unsigned* __restrict__ gH) {
    int y = blockIdx.y, s = y >> 1, which = y & 1;
    const float* src = which ? gt : pred;
    __shared__ unsigned wh[4][NB];
    int t = threadIdx.x, w = t >> 6;
    for (int i = t; i < 4 * NB; i += 256) ((unsigned*)wh)[i] = 0;
    __syncthreads();
    float bw  = maxv[s] * (1.0f / 64.0f);
    float inv = 1.0f / bw;
    const float4* s4 = (const float4*)(src + s * N);
    int base = blockIdx.x * 1024;                       // in float4 units
    for (int k = 0; k < 4; k++) {
        float4 v = s4[base + k * 256 + t];
        float vv[4] = {v.x, v.y, v.z, v.w};
        #pragma unroll
        for (int q = 0; q < 4; q++) {
            float x = vv[q] * inv;                      // x = mag / bin_width >= 0
            int j0 = (int)x;
            float fr = x - (float)j0;
            if (j0 < NB)     atomicAdd(&wh[w][j0],     (unsigned)((1.0f - fr) * SCALE + 0.5f));
            if (j0 + 1 < NB) atomicAdd(&wh[w][j0 + 1], (unsigned)(fr * SCALE + 0.5f));
        }
    }
    __syncthreads();
    unsigned* dst = (which ? gH : pH) + s * NB;
    if (t < NB) {
        unsigned tot = wh[0][t] + wh[1][t] + wh[2][t] + wh[3][t];
        atomicAdd(&dst[t], tot);
    }
}

// ---------------- pass 6: normalize, weight, reduce -------------------------
__global__ __launch_bounds__(256) void k_final(const unsigned* __restrict__ pH,
                                               const unsigned* __restrict__ gH,
                                               float* __restrict__ out) {
    int t = threadIdx.x, s = t >> 6, l = t & 63;        // 4 waves, one per sample
    double ph = (double)pH[s * NB + l];
    double gh = (double)gH[s * NB + l];
    double hp = ph, hg = gh;
    for (int m = 1; m < 64; m <<= 1) { hp += __shfl_xor(hp, m, 64); hg += __shfl_xor(hg, m, 64); }
    double wj = exp(0.4 * (double)l / 64.0);
    double d  = fabs(ph / hp * wj - gh / hg * wj);
    for (int m = 1; m < 64; m <<= 1) d += __shfl_xor(d, m, 64);
    __shared__ double L[4];
    if (l == 0) L[s] = d / 64.0;
    __syncthreads();
    if (t == 0) out[0] = (float)((L[0] + L[1] + L[2] + L[3]) * 0.25);
}

extern "C" void kernel_launch(void* const* d_in, const int* in_sizes, int n_in,
                              void* d_out, int out_size, void* d_ws, size_t ws_size,
                              hipStream_t stream) {
    const float* pred = (const float*)d_in[0];
    const float* gt   = (const float*)d_in[1];
    float* out = (float*)d_out;

    // ws layout (u32 words):
    //   pH[4][64] | gH[4][64] | cnt[4] | scanB[4][3] | maxv[4] (f32)
    //   cand[4][CAP] (f32) | hist[4][P][HB2]  (u16-packed partials, 2 MB)
    unsigned* ws    = (unsigned*)d_ws;
    unsigned* pH    = ws;
    unsigned* gH    = pH + SAMPLES * NB;
    unsigned* cnt   = gH + SAMPLES * NB;
    unsigned* scanB = cnt + SAMPLES;
    float*    maxv  = (float*)(scanB + SAMPLES * 3);
    float*    cand  = maxv + SAMPLES;
    unsigned* hist  = (unsigned*)(cand + SAMPLES * CAP);

    k_hist   <<<dim3(P, SAMPLES), 512, 0, stream>>>(gt, hist);
    k_scan   <<<SAMPLES, 1024, 0, stream>>>(hist, scanB, pH, gH, cnt);
    k_collect<<<dim3(288, SAMPLES), 256, 0, stream>>>(gt, scanB, cnt, cand);
    k_sort   <<<SAMPLES, 1024, 0, stream>>>(cnt, scanB, cand, maxv);
    k_soft   <<<dim3(72, 2 * SAMPLES), 256, 0, stream>>>(pred, gt, maxv, pH, gH);
    k_final  <<<1, 256, 0, stream>>>(pH, gH, out);
}

// Round 4
// 98.040 us; speedup vs baseline: 8.6065x; 1.2622x over previous
//
#include <hip/hip_runtime.h>

#define SAMPLES 4
#define N 294912            // 2*384*384 elements per sample
#define N4 (N / 4)          // 73728 float4 per sample
#define NB 64               // loss histogram bins
#define GB 4096             // coarse value bins: bin = clamp((int)(v*4096),0,4095)
#define CAP 512             // candidate buffer per sample (expected M ~144)
#define R0 280165           // floor(0.95*(N-1)); pos = 280165.45
#define BLK_CAP 64          // per-block candidate staging
#define SCALE 262144.0f     // 2^18 fixed point for soft-hist weights

__device__ __forceinline__ int vbin(float v) {
    int b = (int)(v * 4096.0f);          // monotonic in v for v>=0
    return b < 0 ? 0 : (b > GB - 1 ? GB - 1 : b);
}

// ---------------- pass 1: coarse value histogram, LDS + atomic merge --------
// 256 blocks: 64 per sample, each covers 1152 float4 (4608 elems).
__global__ __launch_bounds__(256) void k_hist(const float* __restrict__ gt,
                                              unsigned* __restrict__ ghist) {
    int b = blockIdx.x, s = b >> 6, p = b & 63, t = threadIdx.x;
    __shared__ unsigned H[GB];
    #pragma unroll
    for (int i = 0; i < GB / 256; i++) H[i * 256 + t] = 0u;
    __syncthreads();
    const float4* src = (const float4*)gt + s * N4 + p * 1152;
    #pragma unroll
    for (int i = 0; i < 4; i++) {
        float4 v = src[i * 256 + t];
        atomicAdd(&H[vbin(v.x)], 1u); atomicAdd(&H[vbin(v.y)], 1u);
        atomicAdd(&H[vbin(v.z)], 1u); atomicAdd(&H[vbin(v.w)], 1u);
    }
    if (t < 128) {
        float4 v = src[1024 + t];
        atomicAdd(&H[vbin(v.x)], 1u); atomicAdd(&H[vbin(v.y)], 1u);
        atomicAdd(&H[vbin(v.z)], 1u); atomicAdd(&H[vbin(v.w)], 1u);
    }
    __syncthreads();
    unsigned* dst = ghist + s * GB;
    #pragma unroll
    for (int k = 0; k < GB / 256; k++) {
        unsigned idx = k * 256 + t;                 // coalesced lines
        unsigned h = H[idx];
        if (h) atomicAdd(&dst[idx], h);
    }
}

// ---------------- pass 2: (redundant scan) + candidate collection -----------
__global__ __launch_bounds__(256) void k_collect(const float* __restrict__ gt,
                                                 const unsigned* __restrict__ ghist,
                                                 unsigned* __restrict__ cnt,
                                                 float* __restrict__ cand,
                                                 unsigned* __restrict__ cumB) {
    int b = blockIdx.x, s = b >> 6, p = b & 63, t = threadIdx.x;
    // --- per-block redundant prefix scan over the sample's 4096 bins ---
    unsigned hbin[16];
    const unsigned* hs = ghist + s * GB + t * 16;
    unsigned sum = 0;
    #pragma unroll
    for (int k = 0; k < 16; k++) { hbin[k] = hs[k]; sum += hbin[k]; }
    __shared__ unsigned S[256];
    __shared__ unsigned sB0, sB1, sCum;
    S[t] = sum;
    __syncthreads();
    for (int off = 1; off < 256; off <<= 1) {
        unsigned v = (t >= off) ? S[t - off] : 0u;
        __syncthreads();
        S[t] += v;
        __syncthreads();
    }
    unsigned incl = S[t], before = incl - sum;
    for (int k = 0; k < 2; k++) {
        unsigned r = R0 + k;
        if (sum > 0 && before <= r && r < incl) {       // unique owner thread
            unsigned c = before;
            #pragma unroll
            for (int bb = 0; bb < 16; bb++) {
                if (r < c + hbin[bb]) {
                    if (k == 0) { sB0 = (unsigned)(t * 16 + bb); sCum = c; }
                    else        { sB1 = (unsigned)(t * 16 + bb); }
                    break;
                }
                c += hbin[bb];
            }
        }
    }
    __syncthreads();
    int B0 = (int)sB0, B1 = (int)sB1;
    if (p == 0 && t == 0) cumB[s] = sCum;
    // --- block-aggregated collection ---
    __shared__ float buf[BLK_CAP];
    __shared__ unsigned nloc, basep;
    if (t == 0) nloc = 0u;
    __syncthreads();
    const float4* src = (const float4*)gt + s * N4 + p * 1152;
    #pragma unroll
    for (int i = 0; i < 4; i++) {
        float4 v = src[i * 256 + t];
        float vv[4] = {v.x, v.y, v.z, v.w};
        #pragma unroll
        for (int q = 0; q < 4; q++) {
            int bi = vbin(vv[q]);
            if (bi >= B0 && bi <= B1) {
                unsigned pp = atomicAdd(&nloc, 1u);
                if (pp < BLK_CAP) buf[pp] = vv[q];
            }
        }
    }
    if (t < 128) {
        float4 v = src[1024 + t];
        float vv[4] = {v.x, v.y, v.z, v.w};
        #pragma unroll
        for (int q = 0; q < 4; q++) {
            int bi = vbin(vv[q]);
            if (bi >= B0 && bi <= B1) {
                unsigned pp = atomicAdd(&nloc, 1u);
                if (pp < BLK_CAP) buf[pp] = vv[q];
            }
        }
    }
    __syncthreads();
    unsigned n = nloc < BLK_CAP ? nloc : BLK_CAP;
    if (t == 0 && n) basep = atomicAdd(&cnt[s], n);     // one global atomic/block
    __syncthreads();
    if (t < n) {
        unsigned pp = basep + t;
        if (pp < CAP) cand[s * CAP + pp] = buf[t];
    }
}

// ---------------- pass 3: (redundant select) + soft hist + fused final ------
// 256 blocks: 32 per (sample, which) map; last block reduces to the loss.
__global__ __launch_bounds__(256) void k_soft(const float* __restrict__ pred,
                                              const float* __restrict__ gt,
                                              const unsigned* __restrict__ cnt,
                                              const float* __restrict__ cand,
                                              const unsigned* __restrict__ cumB,
                                              unsigned* __restrict__ pH,
                                              unsigned* __restrict__ gH,
                                              unsigned* __restrict__ done,
                                              float* __restrict__ out) {
    int b = blockIdx.x, y = b >> 5, p = b & 31, t = threadIdx.x;
    int s = y >> 1, which = y & 1;
    // --- redundant counting select for this sample's 95th percentile ---
    __shared__ float C[CAP];
    __shared__ float vsel[2];
    unsigned M = cnt[s]; if (M > CAP) M = CAP;
    for (int i = t; i < (int)M; i += 256) C[i] = cand[s * CAP + i];
    __syncthreads();
    int t0 = (int)(R0 - cumB[s]);                       // rank within candidates
    float mv0 = (t < (int)M) ? C[t] : 0.f;
    float mv1 = (t + 256 < (int)M) ? C[t + 256] : 0.f;
    int c0 = 0, e0 = 0, c1 = 0, e1 = 0;
    for (unsigned j = 0; j < M; j++) {
        float u = C[j];                                  // broadcast LDS read
        c0 += (u < mv0); e0 += (u == mv0);
        c1 += (u < mv1); e1 += (u == mv1);
    }
    if (t < (int)M) {
        if (c0 <= t0     && t0     < c0 + e0) vsel[0] = mv0;
        if (c0 <= t0 + 1 && t0 + 1 < c0 + e0) vsel[1] = mv0;
    }
    if (t + 256 < (int)M) {
        if (c1 <= t0     && t0     < c1 + e1) vsel[0] = mv1;
        if (c1 <= t0 + 1 && t0 + 1 < c1 + e1) vsel[1] = mv1;
    }
    __syncthreads();
    double gamma = 0.95 * (double)(N - 1) - (double)R0; // 0.45
    float maxv = (float)((double)vsel[0] + gamma * ((double)vsel[1] - (double)vsel[0]));
    // --- soft (triangular) histogram over this block's slice ---
    __shared__ unsigned wh[4][NB];
    int w = t >> 6;
    for (int i = t; i < 4 * NB; i += 256) ((unsigned*)wh)[i] = 0u;
    __syncthreads();
    float bw  = maxv * (1.0f / 64.0f);
    float inv = 1.0f / bw;
    const float* srcm = which ? gt : pred;
    const float4* s4 = (const float4*)(srcm + s * N) + p * 2304;
    #pragma unroll
    for (int i = 0; i < 9; i++) {
        float4 v = s4[i * 256 + t];
        float vv[4] = {v.x, v.y, v.z, v.w};
        #pragma unroll
        for (int q = 0; q < 4; q++) {
            float x = vv[q] * inv;
            int j0 = (int)x;
            float fr = x - (float)j0;
            if (j0 < NB)     atomicAdd(&wh[w][j0],     (unsigned)((1.0f - fr) * SCALE + 0.5f));
            if (j0 + 1 < NB) atomicAdd(&wh[w][j0 + 1], (unsigned)(fr * SCALE + 0.5f));
        }
    }
    __syncthreads();
    unsigned* dst = (which ? gH : pH) + s * NB;
    if (t < NB) atomicAdd(&dst[t], wh[0][t] + wh[1][t] + wh[2][t] + wh[3][t]);
    // --- fused final reduction: last block to finish does it ---
    __threadfence();
    __shared__ unsigned ticket;
    if (t == 0) ticket = atomicAdd(done, 1u);
    __syncthreads();
    if (ticket == 255) {
        int ss = t >> 6, l = t & 63;                    // 4 waves, one per sample
        unsigned phv = __hip_atomic_load(&pH[ss * NB + l], __ATOMIC_RELAXED, __HIP_MEMORY_SCOPE_AGENT);
        unsigned ghv = __hip_atomic_load(&gH[ss * NB + l], __ATOMIC_RELAXED, __HIP_MEMORY_SCOPE_AGENT);
        double ph = (double)phv, gh = (double)ghv;
        double hp = ph, hg = gh;
        for (int m = 1; m < 64; m <<= 1) { hp += __shfl_xor(hp, m, 64); hg += __shfl_xor(hg, m, 64); }
        double wj = exp(0.4 * (double)l / 64.0);
        double d  = fabs(ph / hp * wj - gh / hg * wj);
        for (int m = 1; m < 64; m <<= 1) d += __shfl_xor(d, m, 64);
        __shared__ double L[4];
        if (l == 0) L[ss] = d / 64.0;
        __syncthreads();
        if (t == 0) out[0] = (float)((L[0] + L[1] + L[2] + L[3]) * 0.25);
    }
}

extern "C" void kernel_launch(void* const* d_in, const int* in_sizes, int n_in,
                              void* d_out, int out_size, void* d_ws, size_t ws_size,
                              hipStream_t stream) {
    const float* pred = (const float*)d_in[0];
    const float* gt   = (const float*)d_in[1];
    float* out = (float*)d_out;

    // ws layout (u32 words), zeroed prefix first:
    //   pH[4][64] | gH[4][64] | cnt[4] | done[1] | pad[3] | ghist[4][4096]
    //   (end of zeroed prefix: 16904 words)
    //   cumB[4] | cand[4][CAP] (f32)
    unsigned* ws    = (unsigned*)d_ws;
    unsigned* pH    = ws;
    unsigned* gH    = pH + SAMPLES * NB;
    unsigned* cnt   = gH + SAMPLES * NB;
    unsigned* done  = cnt + SAMPLES;
    unsigned* ghist = done + 4;                         // 16B aligned
    unsigned* cumB  = ghist + SAMPLES * GB;
    float*    cand  = (float*)(cumB + SAMPLES);

    size_t zero_words = 2 * SAMPLES * NB + SAMPLES + 4 + (size_t)SAMPLES * GB; // 16904
    hipMemsetAsync(d_ws, 0, zero_words * sizeof(unsigned), stream);

    k_hist   <<<256, 256, 0, stream>>>(gt, ghist);
    k_collect<<<256, 256, 0, stream>>>(gt, ghist, cnt, cand, cumB);
    k_soft   <<<256, 256, 0, stream>>>(pred, gt, cnt, cand, cumB, pH, gH, done, out);
}